// Round 4
// baseline (99.445 us; speedup 1.0000x reference)
//
#include <hip/hip_runtime.h>

// y[b,t] = tanh(b2[t] + sum_h W2[t,h] * relu(x[b,t]*W1[t,h] + b1[t,h]))
// B=262144, T=30, H=20. Kernel floor: max(HBM 63MB ~10us, VALU 60op/elem ~7us).
// Measured dur also contains ~82us of harness reset (256MiB ws re-poison = 43us
// fill + out fill + d_in restore) that no kernel change can touch.
//
// R4 vs R3 (94.5us): EPT 32->16 doubles grid to 1920 blocks (3.75 -> ~5+
// resident waves/SIMD) and issues ALL 16 loads before any compute -> maximal
// memory-level parallelism per wave, better load/compute overlap across waves.

#define TT 30
#define HH 20
#define BLK 256
#define EPT 16                      // elements per thread; threads % 30 == 0 holds

__global__ __launch_bounds__(BLK) void rnn_mlp_kernel(
    const float* __restrict__ x,
    const float* __restrict__ W1,   // [T][H]
    const float* __restrict__ b1,   // [T][H]
    const float* __restrict__ W2,   // [T][H]
    const float* __restrict__ b2,   // [T]
    float* __restrict__ y,
    int stride)                     // total threads; stride % 30 == 0
{
    const int g = blockIdx.x * BLK + threadIdx.x;
    const int t = g % TT;           // invariant: params load once per thread

    // ---- This thread's 61 params -> VGPRs (7.3 KB total, L1/L2-resident) ----
    const float4* w1v = (const float4*)(W1 + t * HH);
    const float4* b1v = (const float4*)(b1 + t * HH);
    const float4* w2v = (const float4*)(W2 + t * HH);
    float4 w1[5], bb[5], w2[5];
    #pragma unroll
    for (int i = 0; i < 5; ++i) { w1[i] = w1v[i]; bb[i] = b1v[i]; w2[i] = w2v[i]; }
    const float bias2 = b2[t];

    const float* w1f = (const float*)w1;
    const float* bbf = (const float*)bb;
    const float* w2f = (const float*)w2;

    // ---- Issue all 16 coalesced loads up front (max MLP), then compute ----
    float xv[EPT];
    #pragma unroll
    for (int j = 0; j < EPT; ++j)
        xv[j] = x[g + j * stride];      // int math: max index < 2^23

    #pragma unroll
    for (int j = 0; j < EPT; ++j) {
        float acc = bias2;
        #pragma unroll
        for (int h = 0; h < HH; ++h) {
            float a = fmaf(xv[j], w1f[h], bbf[h]);
            acc = fmaf(fmaxf(a, 0.0f), w2f[h], acc);
        }
        // tanh(a) = 1 - 2/(exp(2a)+1); saturates correctly at +/-1.
        float e = __expf(2.0f * acc);
        float r = __builtin_amdgcn_rcpf(e + 1.0f);
        y[g + j * stride] = fmaf(-2.0f, r, 1.0f);
    }
}

extern "C" void kernel_launch(void* const* d_in, const int* in_sizes, int n_in,
                              void* d_out, int out_size, void* d_ws, size_t ws_size,
                              hipStream_t stream) {
    const float* x  = (const float*)d_in[0];   // [B,T,1]
    const float* W1 = (const float*)d_in[1];   // [T,H,1]
    const float* b1 = (const float*)d_in[2];   // [T,H]
    const float* W2 = (const float*)d_in[3];   // [T,1,H]
    const float* b2 = (const float*)d_in[4];   // [T,1]
    float* y = (float*)d_out;

    const int n = in_sizes[0];                 // 7864320 = 491520 * 16
    const int threads = n / EPT;               // 491520; % 30 == 0, % 256 == 0
    const int grid = threads / BLK;            // 1920
    rnn_mlp_kernel<<<grid, BLK, 0, stream>>>(x, W1, b1, W2, b2, y, threads);
}

// Round 5
// 95.359 us; speedup vs baseline: 1.0428x; 1.0428x over previous
//
#include <hip/hip_runtime.h>

// y[b,t] = tanh(b2[t] + sum_h W2[t,h] * relu(x[b,t]*W1[t,h] + b1[t,h]))
// B=262144, T=30, H=20.
// Measured window = ~82us harness reset (256MiB ws 0xAA re-poison = 43us fill
// + out fill + d_in restore) + kernel (~12us). Kernel floors: HBM<=10us
// (x likely L3-warm), VALU ~7us scalar fp32.
//
// R5 vs R3 (94.5us best): keep EPT=32 fixed-t mapping (params load once per
// thread, amortized over 32 elems — R4 proved halving EPT costs ~5us in param
// gather). Changes: (a) all 32 coalesced loads issued up front (max MLP),
// (b) inner MLP computed on element PAIRS via <2 x float> elementwise
// builtins so the backend can select v_pk_fma_f32 / v_pk_max_f32 —
// 2x fp32/instr halves the VALU floor to ~3.5us.

#define TT 30
#define HH 20
#define BLK 256
#define EPT 32

typedef float f32x2 __attribute__((ext_vector_type(2)));

__global__ __launch_bounds__(BLK) void rnn_mlp_kernel(
    const float* __restrict__ x,
    const float* __restrict__ W1,   // [T][H]
    const float* __restrict__ b1,   // [T][H]
    const float* __restrict__ W2,   // [T][H]
    const float* __restrict__ b2,   // [T]
    float* __restrict__ y,
    int stride)                     // total threads; stride % 30 == 0
{
    const int g = blockIdx.x * BLK + threadIdx.x;
    const int t = g % TT;           // invariant: params load once per thread

    // ---- This thread's 61 params -> VGPRs (7.3 KB total, L1/L2-resident) ----
    const float4* w1v = (const float4*)(W1 + t * HH);
    const float4* b1v = (const float4*)(b1 + t * HH);
    const float4* w2v = (const float4*)(W2 + t * HH);
    float4 w1[5], bb[5], w2[5];
    #pragma unroll
    for (int i = 0; i < 5; ++i) { w1[i] = w1v[i]; bb[i] = b1v[i]; w2[i] = w2v[i]; }
    const float bias2 = b2[t];

    const float* w1f = (const float*)w1;
    const float* bbf = (const float*)bb;
    const float* w2f = (const float*)w2;

    // ---- All 32 coalesced loads up front (max memory-level parallelism) ----
    float xv[EPT];
    #pragma unroll
    for (int j = 0; j < EPT; ++j)
        xv[j] = x[g + j * stride];      // int math: max index < 2^23

    // ---- Compute in pairs: <2 x float> ops -> v_pk_fma_f32 / v_pk_max_f32 ----
    #pragma unroll
    for (int j = 0; j < EPT; j += 2) {
        f32x2 xp = { xv[j], xv[j + 1] };
        f32x2 acc = { bias2, bias2 };
        #pragma unroll
        for (int h = 0; h < HH; ++h) {
            f32x2 wp = { w1f[h], w1f[h] };
            f32x2 bp = { bbf[h], bbf[h] };
            f32x2 a = __builtin_elementwise_fma(xp, wp, bp);
            a = __builtin_elementwise_max(a, (f32x2){ 0.0f, 0.0f });
            f32x2 w2p = { w2f[h], w2f[h] };
            acc = __builtin_elementwise_fma(a, w2p, acc);
        }
        // tanh(a) = 1 - 2/(exp(2a)+1); saturates correctly at +/-1.
        float e0 = __expf(2.0f * acc.x);
        float e1 = __expf(2.0f * acc.y);
        float r0 = __builtin_amdgcn_rcpf(e0 + 1.0f);
        float r1 = __builtin_amdgcn_rcpf(e1 + 1.0f);
        y[g + j * stride]       = fmaf(-2.0f, r0, 1.0f);
        y[g + (j + 1) * stride] = fmaf(-2.0f, r1, 1.0f);
    }
}

extern "C" void kernel_launch(void* const* d_in, const int* in_sizes, int n_in,
                              void* d_out, int out_size, void* d_ws, size_t ws_size,
                              hipStream_t stream) {
    const float* x  = (const float*)d_in[0];   // [B,T,1]
    const float* W1 = (const float*)d_in[1];   // [T,H,1]
    const float* b1 = (const float*)d_in[2];   // [T,H]
    const float* W2 = (const float*)d_in[3];   // [T,1,H]
    const float* b2 = (const float*)d_in[4];   // [T,1]
    float* y = (float*)d_out;

    const int n = in_sizes[0];                 // 7864320 = 245760 * 32
    const int threads = n / EPT;               // 245760; % 30 == 0, % 256 == 0
    const int grid = threads / BLK;            // 960
    rnn_mlp_kernel<<<grid, BLK, 0, stream>>>(x, W1, b1, W2, b2, y, threads);
}